// Round 4
// 270.952 us; speedup vs baseline: 1.0048x; 1.0048x over previous
//
#include <hip/hip_runtime.h>
#include <hip/hip_bf16.h>

typedef unsigned short u16;
typedef __attribute__((ext_vector_type(8))) short short8;
typedef __attribute__((ext_vector_type(8))) unsigned short ushort8v;
typedef __attribute__((ext_vector_type(4))) float floatx4;

#define BSZ   4
#define CDIM  512
#define NDIM  512
#define SDIM  64
#define LEN   8192

__device__ __forceinline__ u16 f2bf(float x) {
    unsigned int u = __float_as_uint(x);
    unsigned int r = (u + 0x7FFFu + ((u >> 16) & 1u)) >> 16;
    return (u16)r;
}

#define GLL16(g, l)                                                          \
    __builtin_amdgcn_global_load_lds(                                        \
        (const __attribute__((address_space(1))) unsigned int*)(g),          \
        (__attribute__((address_space(3))) unsigned int*)(l), 16, 0, 0)

// ---------------------------------------------------------------------------
// Per-n prep (block = n): fill Af [n][t=128][k=256] and WW [n][q=128][tau=128].
// Also folds the B/C fp32->bf16 weight conversion (512 elems each per block).
// ---------------------------------------------------------------------------
__global__ __launch_bounds__(256) void prep_nw(const float* __restrict__ dAr,
                                               const float* __restrict__ dAi,
                                               const float* __restrict__ E,
                                               u16* __restrict__ Af,
                                               u16* __restrict__ WW,
                                               const float* __restrict__ Bmf,
                                               const float* __restrict__ Cmf,
                                               u16* __restrict__ bh,
                                               u16* __restrict__ ch) {
    __shared__ float sA[64], sW[64], sE[64];
    __shared__ float Ms[128][65];
    __shared__ float sK[128];
    const int n = blockIdx.x;
    const int t = threadIdx.x;
    if (t < 64) {
        sA[t] = dAr[n * 64 + t];
        sW[t] = dAi[n * 64 + t];
        sE[t] = E[n * 64 + t];
    }
    // folded weight conversion (independent of barriers)
    {
        int i = n * 512 + t * 2;
        float2 vb = *(const float2*)&Bmf[i];
        float2 vc = *(const float2*)&Cmf[i];
        ushort2 hb, hc;
        hb.x = f2bf(vb.x); hb.y = f2bf(vb.y);
        hc.x = f2bf(vc.x); hc.y = f2bf(vc.y);
        *(ushort2*)&bh[i] = hb;
        *(ushort2*)&ch[i] = hc;
    }
    __syncthreads();
    u16* Afn = Af + (size_t)n * 32768;
    // M-part: 128 t x 64 s = 8192 pairs, 32 iters
#pragma unroll 4
    for (int it = 0; it < 32; ++it) {
        int idx = it * 256 + t;
        int tt = idx >> 6, s = idx & 63;
        float a = sA[s], w = sW[s], e = sE[s];
        float tp1 = (float)(tt + 1);
        float sn, cs;
        __sincosf(w * tp1, &sn, &cs);
        float ea = __expf(a * tp1) * e;
        float mr = ea * cs;
        Ms[tt][s] = mr;
        Afn[tt * 256 + 128 + s] = f2bf(mr);
        Afn[tt * 256 + 192 + s] = f2bf(-ea * sn);
    }
    __syncthreads();
    if (t < 128) {
        float acc = 0.f;
        if (t == 0) {
#pragma unroll
            for (int s = 0; s < 64; ++s) acc += sE[s];
        } else {
#pragma unroll
            for (int s = 0; s < 64; ++s) acc += Ms[t - 1][s];
        }
        sK[t] = acc;
    }
    __syncthreads();
    // Toeplitz: 128 t x 128 k = 16384, 64 iters
#pragma unroll 8
    for (int it = 0; it < 64; ++it) {
        int idx = it * 256 + t;
        int tt = idx >> 7, k = idx & 127;
        float v = (k <= tt) ? sK[tt - k] : 0.f;
        Afn[tt * 256 + k] = f2bf(v);
    }
    // WW: 64 s x 128 tau = 8192 pairs, 32 iters
    u16* WWn = WW + (size_t)n * 16384;
#pragma unroll 4
    for (int it = 0; it < 32; ++it) {
        int idx = it * 256 + t;
        int s = idx >> 7, tau = idx & 127;
        float a = sA[s], w = sW[s];
        float d = (float)(127 - tau);
        float sn, cs;
        __sincosf(w * d, &sn, &cs);
        float ea = __expf(a * d);
        WWn[s * 128 + tau] = f2bf(ea * cs);
        WWn[(s + 64) * 128 + tau] = f2bf(ea * sn);
    }
}

// ---------------------------------------------------------------------------
// Transpose input: src [B][512][8192] fp32 -> dst [B][8192][512] bf16.
// ---------------------------------------------------------------------------
__global__ __launch_bounds__(256) void transpose_in(const float* __restrict__ src,
                                                    u16* __restrict__ dst) {
    __shared__ float tile[64][65];
    const int b  = blockIdx.z;
    const int r0 = blockIdx.y * 64;
    const int c0 = blockIdx.x * 64;
    const int t  = threadIdx.x;
    const float* s = src + (size_t)b * 512 * 8192;
#pragma unroll
    for (int p = 0; p < 4; ++p) {
        int r = (t >> 4) + p * 16;
        float4 v = *(const float4*)&s[(size_t)(r0 + r) * 8192 + c0 + (t & 15) * 4];
        tile[r][(t & 15) * 4 + 0] = v.x;
        tile[r][(t & 15) * 4 + 1] = v.y;
        tile[r][(t & 15) * 4 + 2] = v.z;
        tile[r][(t & 15) * 4 + 3] = v.w;
    }
    __syncthreads();
#pragma unroll
    for (int p = 0; p < 4; ++p) {
        int i  = (t >> 4) + p * 16;
        int cb = (t & 15) * 4;
        ushort4 h;
        u16* hp = (u16*)&h;
#pragma unroll
        for (int q = 0; q < 4; ++q) hp[q] = f2bf(tile[cb + q][i]);
        *(ushort4*)&dst[((size_t)b * 8192 + c0 + i) * 512 + r0 + cb] = h;
    }
}

// ---------------------------------------------------------------------------
// Transpose u16: src [B][512][8192] -> dst [B][8192][512].
// ---------------------------------------------------------------------------
__global__ __launch_bounds__(256) void transpose_u16(const u16* __restrict__ src,
                                                     u16* __restrict__ dst) {
    __shared__ u16 tile[64][72];   // 144 B rows (16B-aligned)
    const int b  = blockIdx.z;
    const int n0 = blockIdx.y * 64;
    const int l0 = blockIdx.x * 64;
    const int t  = threadIdx.x;
    const u16* s = src + (size_t)b * 512 * 8192;
    u16* d = dst + (size_t)b * 8192 * 512;
#pragma unroll
    for (int p = 0; p < 2; ++p) {
        int r = (t >> 3) + p * 32;
        *(ushort8v*)&tile[r][(t & 7) * 8] =
            *(const ushort8v*)&s[(size_t)(n0 + r) * 8192 + l0 + (t & 7) * 8];
    }
    __syncthreads();
#pragma unroll
    for (int p = 0; p < 2; ++p) {
        int li = (t >> 3) + p * 32;
        int cb = (t & 7) * 8;
        ushort8v v;
#pragma unroll
        for (int q = 0; q < 8; ++q) v[q] = tile[cb + q][li];
        *(ushort8v*)&d[(size_t)(l0 + li) * 512 + n0 + cb] = v;
    }
}

// ---------------------------------------------------------------------------
// Pure-bf16 MFMA GEMM, bf16 output: Y[b][m][l] = sum_k A[m][k]*Xt[b][l][k]
// ---------------------------------------------------------------------------
__global__ __launch_bounds__(256) void gemm_bf16_o16(const u16* __restrict__ A,
                                                     const u16* __restrict__ Xt,
                                                     u16* __restrict__ Y) {
    __shared__ u16 As[128 * 32];
    __shared__ u16 Xs[128 * 32];
    const int b    = blockIdx.z;
    const int m0   = blockIdx.y * 128;
    const int l0   = blockIdx.x * 128;
    const int t    = threadIdx.x;
    const int w    = t >> 6;
    const int lane = t & 63;
    const int mq   = (w >> 1) * 64;
    const int lq   = (w & 1) * 64;
    const u16* Xb = Xt + (size_t)b * 8192 * 512;
    const size_t a_off = (size_t)(m0 + 32 * w + (lane >> 2)) * 512 + (lane & 3) * 8;
    const size_t x_off = (size_t)(l0 + 32 * w + (lane >> 2)) * 512 + (lane & 3) * 8;
    u16* AsW = As + w * 1024;
    u16* XsW = Xs + w * 1024;

    floatx4 acc[4][4];
#pragma unroll
    for (int i = 0; i < 4; ++i)
#pragma unroll
        for (int j = 0; j < 4; ++j) acc[i][j] = (floatx4)0.f;
    const int fr = lane & 15;
    const int fk = (lane >> 4) * 8;

    for (int k0 = 0; k0 < 512; k0 += 32) {
        __syncthreads();
        GLL16(A + a_off + k0, AsW);
        GLL16(A + a_off + 16 * 512 + k0, AsW + 512);
        GLL16(Xb + x_off + k0, XsW);
        GLL16(Xb + x_off + 16 * 512 + k0, XsW + 512);
        __syncthreads();
        short8 af[4], bf[4];
#pragma unroll
        for (int i = 0; i < 4; ++i) {
            af[i] = *(const short8*)&As[(mq + i * 16 + fr) * 32 + fk];
            bf[i] = *(const short8*)&Xs[(lq + i * 16 + fr) * 32 + fk];
        }
#pragma unroll
        for (int i = 0; i < 4; ++i)
#pragma unroll
            for (int j = 0; j < 4; ++j)
                acc[i][j] = __builtin_amdgcn_mfma_f32_16x16x32_bf16(
                    af[i], bf[j], acc[i][j], 0, 0, 0);
    }
    u16* Yb = Y + (size_t)b * 512 * 8192;
#pragma unroll
    for (int i = 0; i < 4; ++i)
#pragma unroll
        for (int j = 0; j < 4; ++j)
#pragma unroll
            for (int r = 0; r < 4; ++r) {
                int mg = m0 + mq + i * 16 + (lane >> 4) * 4 + r;
                int lg = l0 + lq + j * 16 + (lane & 15);
                Yb[(size_t)mg * 8192 + lg] = f2bf(acc[i][j][r]);
            }
}

// ---------------------------------------------------------------------------
// Pure-bf16 MFMA GEMM, fp32 output (final projection).
// ---------------------------------------------------------------------------
__global__ __launch_bounds__(256) void gemm_bf16_o32(const u16* __restrict__ A,
                                                     const u16* __restrict__ Xt,
                                                     float* __restrict__ Y) {
    __shared__ u16 As[128 * 32];
    __shared__ u16 Xs[128 * 32];
    const int b    = blockIdx.z;
    const int m0   = blockIdx.y * 128;
    const int l0   = blockIdx.x * 128;
    const int t    = threadIdx.x;
    const int w    = t >> 6;
    const int lane = t & 63;
    const int mq   = (w >> 1) * 64;
    const int lq   = (w & 1) * 64;
    const u16* Xb = Xt + (size_t)b * 8192 * 512;
    const size_t a_off = (size_t)(m0 + 32 * w + (lane >> 2)) * 512 + (lane & 3) * 8;
    const size_t x_off = (size_t)(l0 + 32 * w + (lane >> 2)) * 512 + (lane & 3) * 8;
    u16* AsW = As + w * 1024;
    u16* XsW = Xs + w * 1024;

    floatx4 acc[4][4];
#pragma unroll
    for (int i = 0; i < 4; ++i)
#pragma unroll
        for (int j = 0; j < 4; ++j) acc[i][j] = (floatx4)0.f;
    const int fr = lane & 15;
    const int fk = (lane >> 4) * 8;

    for (int k0 = 0; k0 < 512; k0 += 32) {
        __syncthreads();
        GLL16(A + a_off + k0, AsW);
        GLL16(A + a_off + 16 * 512 + k0, AsW + 512);
        GLL16(Xb + x_off + k0, XsW);
        GLL16(Xb + x_off + 16 * 512 + k0, XsW + 512);
        __syncthreads();
        short8 af[4], bf[4];
#pragma unroll
        for (int i = 0; i < 4; ++i) {
            af[i] = *(const short8*)&As[(mq + i * 16 + fr) * 32 + fk];
            bf[i] = *(const short8*)&Xs[(lq + i * 16 + fr) * 32 + fk];
        }
#pragma unroll
        for (int i = 0; i < 4; ++i)
#pragma unroll
            for (int j = 0; j < 4; ++j)
                acc[i][j] = __builtin_amdgcn_mfma_f32_16x16x32_bf16(
                    af[i], bf[j], acc[i][j], 0, 0, 0);
    }
    float* Yb = Y + (size_t)b * 512 * 8192;
#pragma unroll
    for (int i = 0; i < 4; ++i)
#pragma unroll
        for (int j = 0; j < 4; ++j)
#pragma unroll
            for (int r = 0; r < 4; ++r) {
                int mg = m0 + mq + i * 16 + (lane >> 4) * 4 + r;
                int lg = l0 + lq + j * 16 + (lane & 15);
                Yb[(size_t)mg * 8192 + lg] = acc[i][j][r];
            }
}

// ---------------------------------------------------------------------------
// SE-GEMM: per n, SE[c][q] = sum_tau x[c][tau] * WW[n][q][tau]
// ---------------------------------------------------------------------------
__global__ __launch_bounds__(256) void se_gemm(const u16* __restrict__ xbf,
                                               const u16* __restrict__ WW,
                                               u16* __restrict__ SEf) {
    __shared__ u16 As[128 * 32];
    __shared__ u16 Bs[128 * 32];
    const int n  = blockIdx.y;
    const int c0 = blockIdx.x * 128;
    const int t  = threadIdx.x;
    const int w  = t >> 6, lane = t & 63;
    const int mq = (w >> 1) * 64;
    const int lq = (w & 1) * 64;
    const int ar0 = 32 * w + (lane >> 2);
    const int kq8 = (lane & 3) * 8;
    const int c_a0 = c0 + ar0, c_a1 = c_a0 + 16;
    const size_t xrow0 = ((size_t)(c_a0 >> 6) * 512 + n) * 8192 + (size_t)(c_a0 & 63) * 128 + kq8;
    const size_t xrow1 = ((size_t)(c_a1 >> 6) * 512 + n) * 8192 + (size_t)(c_a1 & 63) * 128 + kq8;
    const size_t brow0 = (size_t)n * 16384 + (size_t)ar0 * 128 + kq8;
    const size_t brow1 = brow0 + 16 * 128;
    const int wofs = w * 1024;

    floatx4 acc[4][4];
#pragma unroll
    for (int i = 0; i < 4; ++i)
#pragma unroll
        for (int j = 0; j < 4; ++j) acc[i][j] = (floatx4)0.f;
    const int fr = lane & 15, fk = (lane >> 4) * 8;

    for (int k0 = 0; k0 < 128; k0 += 32) {
        __syncthreads();
        GLL16(xbf + xrow0 + k0, As + wofs);
        GLL16(xbf + xrow1 + k0, As + wofs + 512);
        GLL16(WW + brow0 + k0, Bs + wofs);
        GLL16(WW + brow1 + k0, Bs + wofs + 512);
        __syncthreads();
        short8 af[4], bf[4];
#pragma unroll
        for (int i = 0; i < 4; ++i) {
            af[i] = *(const short8*)&As[(mq + i * 16 + fr) * 32 + fk];
            bf[i] = *(const short8*)&Bs[(lq + i * 16 + fr) * 32 + fk];
        }
#pragma unroll
        for (int i = 0; i < 4; ++i)
#pragma unroll
            for (int j = 0; j < 4; ++j)
                acc[i][j] = __builtin_amdgcn_mfma_f32_16x16x32_bf16(
                    af[i], bf[j], acc[i][j], 0, 0, 0);
    }
#pragma unroll
    for (int i = 0; i < 4; ++i)
#pragma unroll
        for (int j = 0; j < 4; ++j)
#pragma unroll
            for (int r = 0; r < 4; ++r) {
                int c = c0 + mq + i * 16 + (lane >> 4) * 4 + r;
                int q = lq + j * 16 + (lane & 15);
                SEf[(((size_t)(c >> 6) * 512 + n) * 64 + (c & 63)) * 128 + q] =
                    f2bf(acc[i][j][r]);
            }
}

// ---------------------------------------------------------------------------
// Boundary scan: H[j+1] = z^T * H[j] + SE[j], H[0]=0; store H[j] (bf16).
// ---------------------------------------------------------------------------
__global__ __launch_bounds__(256) void bscan(const float* __restrict__ dAr,
                                             const float* __restrict__ dAi,
                                             const u16* __restrict__ SEf,
                                             u16* __restrict__ Ht) {
    const int id = blockIdx.x * 256 + threadIdx.x;
    const int s = id & 63, n = (id >> 6) & 511, b = id >> 15;
    const float a = dAr[n * 64 + s], wv = dAi[n * 64 + s];
    const float eaT = expf(a * 128.f);
    float sT, cT;
    sincosf(wv * 128.f, &sT, &cT);
    const float zTr = eaT * cT, zTi = eaT * sT;
    const size_t base = ((size_t)b * 512 + n) * 64 * 128;
    float Hr = 0.f, Hi = 0.f;
    for (int j = 0; j < 64; ++j) {
        Ht[base + j * 128 + s]      = f2bf(Hr);
        Ht[base + j * 128 + 64 + s] = f2bf(Hi);
        float ser = __uint_as_float((unsigned int)SEf[base + j * 128 + s] << 16);
        float sei = __uint_as_float((unsigned int)SEf[base + j * 128 + 64 + s] << 16);
        float nHr = fmaf(zTr, Hr, fmaf(-zTi, Hi, ser));
        float nHi = fmaf(zTi, Hr, fmaf(zTr, Hi, sei));
        Hr = nHr; Hi = nHi;
    }
}

// ---------------------------------------------------------------------------
// y-GEMM: y[c][t] = [x ; H](c, k) dot Afull[n][t][k], K=256. bf16 output.
// ---------------------------------------------------------------------------
__global__ __launch_bounds__(256) void y_gemm(const u16* __restrict__ xbf,
                                              const u16* __restrict__ Ht,
                                              const u16* __restrict__ Af,
                                              u16* __restrict__ wyb) {
    __shared__ u16 As[128 * 32];
    __shared__ u16 Bs[128 * 32];
    const int n  = blockIdx.y;
    const int c0 = blockIdx.x * 128;
    const int t  = threadIdx.x;
    const int w  = t >> 6, lane = t & 63;
    const int mq = (w >> 1) * 64;
    const int lq = (w & 1) * 64;
    const int ar0 = 32 * w + (lane >> 2);
    const int kq8 = (lane & 3) * 8;
    const int c_a0 = c0 + ar0, c_a1 = c_a0 + 16;
    const size_t xrow0 = ((size_t)(c_a0 >> 6) * 512 + n) * 8192 + (size_t)(c_a0 & 63) * 128 + kq8;
    const size_t xrow1 = ((size_t)(c_a1 >> 6) * 512 + n) * 8192 + (size_t)(c_a1 & 63) * 128 + kq8;
    const size_t hrow0 = (((size_t)(c_a0 >> 6) * 512 + n) * 64 + (c_a0 & 63)) * 128 + kq8;
    const size_t hrow1 = (((size_t)(c_a1 >> 6) * 512 + n) * 64 + (c_a1 & 63)) * 128 + kq8;
    const size_t brow0 = (size_t)n * 32768 + (size_t)ar0 * 256 + kq8;
    const size_t brow1 = brow0 + 16 * 256;
    const int wofs = w * 1024;

    floatx4 acc[4][4];
#pragma unroll
    for (int i = 0; i < 4; ++i)
#pragma unroll
        for (int j = 0; j < 4; ++j) acc[i][j] = (floatx4)0.f;
    const int fr = lane & 15, fk = (lane >> 4) * 8;

    for (int k0 = 0; k0 < 256; k0 += 32) {
        __syncthreads();
        if (k0 < 128) {
            GLL16(xbf + xrow0 + k0, As + wofs);
            GLL16(xbf + xrow1 + k0, As + wofs + 512);
        } else {
            GLL16(Ht + hrow0 + (k0 - 128), As + wofs);
            GLL16(Ht + hrow1 + (k0 - 128), As + wofs + 512);
        }
        GLL16(Af + brow0 + k0, Bs + wofs);
        GLL16(Af + brow1 + k0, Bs + wofs + 512);
        __syncthreads();
        short8 af[4], bf[4];
#pragma unroll
        for (int i = 0; i < 4; ++i) {
            af[i] = *(const short8*)&As[(mq + i * 16 + fr) * 32 + fk];
            bf[i] = *(const short8*)&Bs[(lq + i * 16 + fr) * 32 + fk];
        }
#pragma unroll
        for (int i = 0; i < 4; ++i)
#pragma unroll
            for (int j = 0; j < 4; ++j)
                acc[i][j] = __builtin_amdgcn_mfma_f32_16x16x32_bf16(
                    af[i], bf[j], acc[i][j], 0, 0, 0);
    }
#pragma unroll
    for (int i = 0; i < 4; ++i)
#pragma unroll
        for (int j = 0; j < 4; ++j)
#pragma unroll
            for (int r = 0; r < 4; ++r) {
                int c  = c0 + mq + i * 16 + (lane >> 4) * 4 + r;
                int tc = lq + j * 16 + (lane & 15);
                wyb[((size_t)(c >> 6) * 512 + n) * 8192 + (size_t)(c & 63) * 128 + tc] =
                    f2bf(acc[i][j][r]);
            }
}

// ---------------------------------------------------------------------------
extern "C" void kernel_launch(void* const* d_in, const int* in_sizes, int n_in,
                              void* d_out, int out_size, void* d_ws, size_t ws_size,
                              hipStream_t stream) {
    const float* input = (const float*)d_in[0];  // [B, C, L]
    const float* dAr   = (const float*)d_in[1];
    const float* dAi   = (const float*)d_in[2];
    const float* Bm    = (const float*)d_in[3];  // [N, C]
    const float* Cm    = (const float*)d_in[4];  // [C, N]
    const float* E     = (const float*)d_in[5];
    float* out = (float*)d_out;

    char* ws = (char*)d_ws;
    const size_t MB = 1048576;
    u16* xt   = (u16*)(ws + 0);          // 32 MB  (later overlaid by wyb)
    u16* xbf  = (u16*)(ws + 32 * MB);    // 32 MB  (later overlaid by yt)
    u16* Af   = (u16*)(ws + 64 * MB);    // 32 MB
    u16* WW   = (u16*)(ws + 96 * MB);    // 16 MB
    u16* SEf  = (u16*)(ws + 112 * MB);   // 32 MB
    u16* Ht   = (u16*)(ws + 144 * MB);   // 32 MB
    u16* Bmb  = (u16*)(ws + 176 * MB);   // 0.5 MB
    u16* Cmb  = (u16*)(ws + 177 * MB);   // 0.5 MB
    u16* wyb  = xt;                      // overlay (xt dead after gemm1)
    u16* yt   = xbf;                     // overlay (xbf dead after y_gemm)

    prep_nw<<<512, 256, 0, stream>>>(dAr, dAi, E, Af, WW, Bm, Cm, Bmb, Cmb);
    transpose_in<<<dim3(128, 8, BSZ), 256, 0, stream>>>(input, xt);
    gemm_bf16_o16<<<dim3(64, 4, BSZ), 256, 0, stream>>>(Bmb, xt, xbf);
    se_gemm<<<dim3(2, 512), 256, 0, stream>>>(xbf, WW, SEf);
    bscan<<<512, 256, 0, stream>>>(dAr, dAi, SEf, Ht);
    y_gemm<<<dim3(2, 512), 256, 0, stream>>>(xbf, Ht, Af, wyb);
    transpose_u16<<<dim3(128, 8, BSZ), 256, 0, stream>>>(wyb, yt);
    gemm_bf16_o32<<<dim3(64, 4, BSZ), 256, 0, stream>>>(Cmb, yt, out);
}

// Round 7
// 268.089 us; speedup vs baseline: 1.0155x; 1.0107x over previous
//
#include <hip/hip_runtime.h>
#include <hip/hip_bf16.h>

typedef unsigned short u16;
typedef __attribute__((ext_vector_type(8))) short short8;
typedef __attribute__((ext_vector_type(8))) unsigned short ushort8v;
typedef __attribute__((ext_vector_type(4))) float floatx4;

#define BSZ   4
#define CDIM  512
#define NDIM  512
#define SDIM  64
#define LEN   8192

__device__ __forceinline__ u16 f2bf(float x) {
    unsigned int u = __float_as_uint(x);
    unsigned int r = (u + 0x7FFFu + ((u >> 16) & 1u)) >> 16;
    return (u16)r;
}

#define GLL16(g, l)                                                          \
    __builtin_amdgcn_global_load_lds(                                        \
        (const __attribute__((address_space(1))) unsigned int*)(g),          \
        (__attribute__((address_space(3))) unsigned int*)(l), 16, 0, 0)

// ---------------------------------------------------------------------------
// Per-n prep (block = n): fill Af [n][t=128][k=256] and WW [n][q=128][tau=128].
// Also folds the B/C fp32->bf16 weight conversion (512 elems each per block).
// ---------------------------------------------------------------------------
__global__ __launch_bounds__(256) void prep_nw(const float* __restrict__ dAr,
                                               const float* __restrict__ dAi,
                                               const float* __restrict__ E,
                                               u16* __restrict__ Af,
                                               u16* __restrict__ WW,
                                               const float* __restrict__ Bmf,
                                               const float* __restrict__ Cmf,
                                               u16* __restrict__ bh,
                                               u16* __restrict__ ch) {
    __shared__ float sA[64], sW[64], sE[64];
    __shared__ float Ms[128][65];
    __shared__ float sK[128];
    const int n = blockIdx.x;
    const int t = threadIdx.x;
    if (t < 64) {
        sA[t] = dAr[n * 64 + t];
        sW[t] = dAi[n * 64 + t];
        sE[t] = E[n * 64 + t];
    }
    // folded weight conversion (independent of barriers)
    {
        int i = n * 512 + t * 2;
        float2 vb = *(const float2*)&Bmf[i];
        float2 vc = *(const float2*)&Cmf[i];
        ushort2 hb, hc;
        hb.x = f2bf(vb.x); hb.y = f2bf(vb.y);
        hc.x = f2bf(vc.x); hc.y = f2bf(vc.y);
        *(ushort2*)&bh[i] = hb;
        *(ushort2*)&ch[i] = hc;
    }
    __syncthreads();
    u16* Afn = Af + (size_t)n * 32768;
    // M-part: 128 t x 64 s = 8192 pairs, 32 iters
#pragma unroll 4
    for (int it = 0; it < 32; ++it) {
        int idx = it * 256 + t;
        int tt = idx >> 6, s = idx & 63;
        float a = sA[s], w = sW[s], e = sE[s];
        float tp1 = (float)(tt + 1);
        float sn, cs;
        __sincosf(w * tp1, &sn, &cs);
        float ea = __expf(a * tp1) * e;
        float mr = ea * cs;
        Ms[tt][s] = mr;
        Afn[tt * 256 + 128 + s] = f2bf(mr);
        Afn[tt * 256 + 192 + s] = f2bf(-ea * sn);
    }
    __syncthreads();
    if (t < 128) {
        float acc = 0.f;
        if (t == 0) {
#pragma unroll
            for (int s = 0; s < 64; ++s) acc += sE[s];
        } else {
#pragma unroll
            for (int s = 0; s < 64; ++s) acc += Ms[t - 1][s];
        }
        sK[t] = acc;
    }
    __syncthreads();
    // Toeplitz: 128 t x 128 k = 16384, 64 iters
#pragma unroll 8
    for (int it = 0; it < 64; ++it) {
        int idx = it * 256 + t;
        int tt = idx >> 7, k = idx & 127;
        float v = (k <= tt) ? sK[tt - k] : 0.f;
        Afn[tt * 256 + k] = f2bf(v);
    }
    // WW: 64 s x 128 tau = 8192 pairs, 32 iters
    u16* WWn = WW + (size_t)n * 16384;
#pragma unroll 4
    for (int it = 0; it < 32; ++it) {
        int idx = it * 256 + t;
        int s = idx >> 7, tau = idx & 127;
        float a = sA[s], w = sW[s];
        float d = (float)(127 - tau);
        float sn, cs;
        __sincosf(w * d, &sn, &cs);
        float ea = __expf(a * d);
        WWn[s * 128 + tau] = f2bf(ea * cs);
        WWn[(s + 64) * 128 + tau] = f2bf(ea * sn);
    }
}

// ---------------------------------------------------------------------------
// Transpose input: src [B][512][8192] fp32 -> dst [B][8192][512] bf16.
// ---------------------------------------------------------------------------
__global__ __launch_bounds__(256) void transpose_in(const float* __restrict__ src,
                                                    u16* __restrict__ dst) {
    __shared__ float tile[64][65];
    const int b  = blockIdx.z;
    const int r0 = blockIdx.y * 64;
    const int c0 = blockIdx.x * 64;
    const int t  = threadIdx.x;
    const float* s = src + (size_t)b * 512 * 8192;
#pragma unroll
    for (int p = 0; p < 4; ++p) {
        int r = (t >> 4) + p * 16;
        float4 v = *(const float4*)&s[(size_t)(r0 + r) * 8192 + c0 + (t & 15) * 4];
        tile[r][(t & 15) * 4 + 0] = v.x;
        tile[r][(t & 15) * 4 + 1] = v.y;
        tile[r][(t & 15) * 4 + 2] = v.z;
        tile[r][(t & 15) * 4 + 3] = v.w;
    }
    __syncthreads();
#pragma unroll
    for (int p = 0; p < 4; ++p) {
        int i  = (t >> 4) + p * 16;
        int cb = (t & 15) * 4;
        ushort4 h;
        u16* hp = (u16*)&h;
#pragma unroll
        for (int q = 0; q < 4; ++q) hp[q] = f2bf(tile[cb + q][i]);
        *(ushort4*)&dst[((size_t)b * 8192 + c0 + i) * 512 + r0 + cb] = h;
    }
}

// ---------------------------------------------------------------------------
// Transpose u16: src [B][512][8192] -> dst [B][8192][512].
// ---------------------------------------------------------------------------
__global__ __launch_bounds__(256) void transpose_u16(const u16* __restrict__ src,
                                                     u16* __restrict__ dst) {
    __shared__ u16 tile[64][72];   // 144 B rows (16B-aligned)
    const int b  = blockIdx.z;
    const int n0 = blockIdx.y * 64;
    const int l0 = blockIdx.x * 64;
    const int t  = threadIdx.x;
    const u16* s = src + (size_t)b * 512 * 8192;
    u16* d = dst + (size_t)b * 8192 * 512;
#pragma unroll
    for (int p = 0; p < 2; ++p) {
        int r = (t >> 3) + p * 32;
        *(ushort8v*)&tile[r][(t & 7) * 8] =
            *(const ushort8v*)&s[(size_t)(n0 + r) * 8192 + l0 + (t & 7) * 8];
    }
    __syncthreads();
#pragma unroll
    for (int p = 0; p < 2; ++p) {
        int li = (t >> 3) + p * 32;
        int cb = (t & 7) * 8;
        ushort8v v;
#pragma unroll
        for (int q = 0; q < 8; ++q) v[q] = tile[cb + q][li];
        *(ushort8v*)&d[(size_t)(l0 + li) * 512 + n0 + cb] = v;
    }
}

// ---------------------------------------------------------------------------
// Pure-bf16 MFMA GEMM, bf16 output. BK=64, T2 XOR-swizzled LDS.
//   LDS physical u16 col p at row r holds logical col p ^ ((r&7)<<3).
//   Staging: linear GLL16 dest + pre-swizzled global source col
//   8*((lane&7)^(lane>>3)); read: logical (kk+fk) -> physical ^((row&7)<<3).
//   Accumulation order k = 0,32,64,... identical to BK=32 (bit-exact).
// ---------------------------------------------------------------------------
__global__ __launch_bounds__(256) void gemm_bf16_o16(const u16* __restrict__ A,
                                                     const u16* __restrict__ Xt,
                                                     u16* __restrict__ Y) {
    __shared__ u16 As[128 * 64];
    __shared__ u16 Xs[128 * 64];
    const int b    = blockIdx.z;
    const int m0   = blockIdx.y * 128;
    const int l0   = blockIdx.x * 128;
    const int t    = threadIdx.x;
    const int w    = t >> 6;
    const int lane = t & 63;
    const int mq   = (w >> 1) * 64;
    const int lq   = (w & 1) * 64;
    const u16* Xb = Xt + (size_t)b * 8192 * 512;
    const int scol = (((lane & 7) ^ (lane >> 3)) << 3);   // swizzled source col (u16)
    const size_t a_off = (size_t)(m0 + 32 * w + (lane >> 3)) * 512 + scol;
    const size_t x_off = (size_t)(l0 + 32 * w + (lane >> 3)) * 512 + scol;
    u16* AsW = As + w * 2048;
    u16* XsW = Xs + w * 2048;

    floatx4 acc[4][4];
#pragma unroll
    for (int i = 0; i < 4; ++i)
#pragma unroll
        for (int j = 0; j < 4; ++j) acc[i][j] = (floatx4)0.f;
    const int fr = lane & 15;
    const int fk = (lane >> 4) * 8;
    const int swz = (fr & 7) << 3;   // row-dependent XOR for fragment reads

    for (int k0 = 0; k0 < 512; k0 += 64) {
        __syncthreads();
#pragma unroll
        for (int g = 0; g < 4; ++g) {
            GLL16(A + a_off + g * 4096 + k0, AsW + g * 512);
            GLL16(Xb + x_off + g * 4096 + k0, XsW + g * 512);
        }
        __syncthreads();
#pragma unroll
        for (int kk = 0; kk < 64; kk += 32) {
            short8 af[4], bf[4];
            const int pc = (kk + fk) ^ swz;   // physical col (mq/lq/i*16 are mult of 8)
#pragma unroll
            for (int i = 0; i < 4; ++i) {
                af[i] = *(const short8*)&As[(mq + i * 16 + fr) * 64 + pc];
                bf[i] = *(const short8*)&Xs[(lq + i * 16 + fr) * 64 + pc];
            }
#pragma unroll
            for (int i = 0; i < 4; ++i)
#pragma unroll
                for (int j = 0; j < 4; ++j)
                    acc[i][j] = __builtin_amdgcn_mfma_f32_16x16x32_bf16(
                        af[i], bf[j], acc[i][j], 0, 0, 0);
        }
    }
    u16* Yb = Y + (size_t)b * 512 * 8192;
#pragma unroll
    for (int i = 0; i < 4; ++i)
#pragma unroll
        for (int j = 0; j < 4; ++j)
#pragma unroll
            for (int r = 0; r < 4; ++r) {
                int mg = m0 + mq + i * 16 + (lane >> 4) * 4 + r;
                int lg = l0 + lq + j * 16 + (lane & 15);
                Yb[(size_t)mg * 8192 + lg] = f2bf(acc[i][j][r]);
            }
}

// ---------------------------------------------------------------------------
// Pure-bf16 MFMA GEMM, fp32 output (final projection). BK=64 + T2 swizzle.
// ---------------------------------------------------------------------------
__global__ __launch_bounds__(256) void gemm_bf16_o32(const u16* __restrict__ A,
                                                     const u16* __restrict__ Xt,
                                                     float* __restrict__ Y) {
    __shared__ u16 As[128 * 64];
    __shared__ u16 Xs[128 * 64];
    const int b    = blockIdx.z;
    const int m0   = blockIdx.y * 128;
    const int l0   = blockIdx.x * 128;
    const int t    = threadIdx.x;
    const int w    = t >> 6;
    const int lane = t & 63;
    const int mq   = (w >> 1) * 64;
    const int lq   = (w & 1) * 64;
    const u16* Xb = Xt + (size_t)b * 8192 * 512;
    const int scol = (((lane & 7) ^ (lane >> 3)) << 3);
    const size_t a_off = (size_t)(m0 + 32 * w + (lane >> 3)) * 512 + scol;
    const size_t x_off = (size_t)(l0 + 32 * w + (lane >> 3)) * 512 + scol;
    u16* AsW = As + w * 2048;
    u16* XsW = Xs + w * 2048;

    floatx4 acc[4][4];
#pragma unroll
    for (int i = 0; i < 4; ++i)
#pragma unroll
        for (int j = 0; j < 4; ++j) acc[i][j] = (floatx4)0.f;
    const int fr = lane & 15;
    const int fk = (lane >> 4) * 8;
    const int swz = (fr & 7) << 3;

    for (int k0 = 0; k0 < 512; k0 += 64) {
        __syncthreads();
#pragma unroll
        for (int g = 0; g < 4; ++g) {
            GLL16(A + a_off + g * 4096 + k0, AsW + g * 512);
            GLL16(Xb + x_off + g * 4096 + k0, XsW + g * 512);
        }
        __syncthreads();
#pragma unroll
        for (int kk = 0; kk < 64; kk += 32) {
            short8 af[4], bf[4];
            const int pc = (kk + fk) ^ swz;
#pragma unroll
            for (int i = 0; i < 4; ++i) {
                af[i] = *(const short8*)&As[(mq + i * 16 + fr) * 64 + pc];
                bf[i] = *(const short8*)&Xs[(lq + i * 16 + fr) * 64 + pc];
            }
#pragma unroll
            for (int i = 0; i < 4; ++i)
#pragma unroll
                for (int j = 0; j < 4; ++j)
                    acc[i][j] = __builtin_amdgcn_mfma_f32_16x16x32_bf16(
                        af[i], bf[j], acc[i][j], 0, 0, 0);
        }
    }
    float* Yb = Y + (size_t)b * 512 * 8192;
#pragma unroll
    for (int i = 0; i < 4; ++i)
#pragma unroll
        for (int j = 0; j < 4; ++j)
#pragma unroll
            for (int r = 0; r < 4; ++r) {
                int mg = m0 + mq + i * 16 + (lane >> 4) * 4 + r;
                int lg = l0 + lq + j * 16 + (lane & 15);
                Yb[(size_t)mg * 8192 + lg] = acc[i][j][r];
            }
}

// ---------------------------------------------------------------------------
// SE-GEMM: per n, SE[c][q] = sum_tau x[c][tau] * WW[n][q][tau]
// ---------------------------------------------------------------------------
__global__ __launch_bounds__(256) void se_gemm(const u16* __restrict__ xbf,
                                               const u16* __restrict__ WW,
                                               u16* __restrict__ SEf) {
    __shared__ u16 As[128 * 32];
    __shared__ u16 Bs[128 * 32];
    const int n  = blockIdx.y;
    const int c0 = blockIdx.x * 128;
    const int t  = threadIdx.x;
    const int w  = t >> 6, lane = t & 63;
    const int mq = (w >> 1) * 64;
    const int lq = (w & 1) * 64;
    const int ar0 = 32 * w + (lane >> 2);
    const int kq8 = (lane & 3) * 8;
    const int c_a0 = c0 + ar0, c_a1 = c_a0 + 16;
    const size_t xrow0 = ((size_t)(c_a0 >> 6) * 512 + n) * 8192 + (size_t)(c_a0 & 63) * 128 + kq8;
    const size_t xrow1 = ((size_t)(c_a1 >> 6) * 512 + n) * 8192 + (size_t)(c_a1 & 63) * 128 + kq8;
    const size_t brow0 = (size_t)n * 16384 + (size_t)ar0 * 128 + kq8;
    const size_t brow1 = brow0 + 16 * 128;
    const int wofs = w * 1024;

    floatx4 acc[4][4];
#pragma unroll
    for (int i = 0; i < 4; ++i)
#pragma unroll
        for (int j = 0; j < 4; ++j) acc[i][j] = (floatx4)0.f;
    const int fr = lane & 15, fk = (lane >> 4) * 8;

    for (int k0 = 0; k0 < 128; k0 += 32) {
        __syncthreads();
        GLL16(xbf + xrow0 + k0, As + wofs);
        GLL16(xbf + xrow1 + k0, As + wofs + 512);
        GLL16(WW + brow0 + k0, Bs + wofs);
        GLL16(WW + brow1 + k0, Bs + wofs + 512);
        __syncthreads();
        short8 af[4], bf[4];
#pragma unroll
        for (int i = 0; i < 4; ++i) {
            af[i] = *(const short8*)&As[(mq + i * 16 + fr) * 32 + fk];
            bf[i] = *(const short8*)&Bs[(lq + i * 16 + fr) * 32 + fk];
        }
#pragma unroll
        for (int i = 0; i < 4; ++i)
#pragma unroll
            for (int j = 0; j < 4; ++j)
                acc[i][j] = __builtin_amdgcn_mfma_f32_16x16x32_bf16(
                    af[i], bf[j], acc[i][j], 0, 0, 0);
    }
#pragma unroll
    for (int i = 0; i < 4; ++i)
#pragma unroll
        for (int j = 0; j < 4; ++j)
#pragma unroll
            for (int r = 0; r < 4; ++r) {
                int c = c0 + mq + i * 16 + (lane >> 4) * 4 + r;
                int q = lq + j * 16 + (lane & 15);
                SEf[(((size_t)(c >> 6) * 512 + n) * 64 + (c & 63)) * 128 + q] =
                    f2bf(acc[i][j][r]);
            }
}

// ---------------------------------------------------------------------------
// Boundary scan: H[j+1] = z^T * H[j] + SE[j], H[0]=0; store H[j] (bf16).
// ---------------------------------------------------------------------------
__global__ __launch_bounds__(256) void bscan(const float* __restrict__ dAr,
                                             const float* __restrict__ dAi,
                                             const u16* __restrict__ SEf,
                                             u16* __restrict__ Ht) {
    const int id = blockIdx.x * 256 + threadIdx.x;
    const int s = id & 63, n = (id >> 6) & 511, b = id >> 15;
    const float a = dAr[n * 64 + s], wv = dAi[n * 64 + s];
    const float eaT = expf(a * 128.f);
    float sT, cT;
    sincosf(wv * 128.f, &sT, &cT);
    const float zTr = eaT * cT, zTi = eaT * sT;
    const size_t base = ((size_t)b * 512 + n) * 64 * 128;
    float Hr = 0.f, Hi = 0.f;
    for (int j = 0; j < 64; ++j) {
        Ht[base + j * 128 + s]      = f2bf(Hr);
        Ht[base + j * 128 + 64 + s] = f2bf(Hi);
        float ser = __uint_as_float((unsigned int)SEf[base + j * 128 + s] << 16);
        float sei = __uint_as_float((unsigned int)SEf[base + j * 128 + 64 + s] << 16);
        float nHr = fmaf(zTr, Hr, fmaf(-zTi, Hi, ser));
        float nHi = fmaf(zTi, Hr, fmaf(zTr, Hi, sei));
        Hr = nHr; Hi = nHi;
    }
}

// ---------------------------------------------------------------------------
// y-GEMM: y[c][t] = [x ; H](c, k) dot Afull[n][t][k], K=256. bf16 output.
// ---------------------------------------------------------------------------
__global__ __launch_bounds__(256) void y_gemm(const u16* __restrict__ xbf,
                                              const u16* __restrict__ Ht,
                                              const u16* __restrict__ Af,
                                              u16* __restrict__ wyb) {
    __shared__ u16 As[128 * 32];
    __shared__ u16 Bs[128 * 32];
    const int n  = blockIdx.y;
    const int c0 = blockIdx.x * 128;
    const int t  = threadIdx.x;
    const int w  = t >> 6, lane = t & 63;
    const int mq = (w >> 1) * 64;
    const int lq = (w & 1) * 64;
    const int ar0 = 32 * w + (lane >> 2);
    const int kq8 = (lane & 3) * 8;
    const int c_a0 = c0 + ar0, c_a1 = c_a0 + 16;
    const size_t xrow0 = ((size_t)(c_a0 >> 6) * 512 + n) * 8192 + (size_t)(c_a0 & 63) * 128 + kq8;
    const size_t xrow1 = ((size_t)(c_a1 >> 6) * 512 + n) * 8192 + (size_t)(c_a1 & 63) * 128 + kq8;
    const size_t hrow0 = (((size_t)(c_a0 >> 6) * 512 + n) * 64 + (c_a0 & 63)) * 128 + kq8;
    const size_t hrow1 = (((size_t)(c_a1 >> 6) * 512 + n) * 64 + (c_a1 & 63)) * 128 + kq8;
    const size_t brow0 = (size_t)n * 32768 + (size_t)ar0 * 256 + kq8;
    const size_t brow1 = brow0 + 16 * 256;
    const int wofs = w * 1024;

    floatx4 acc[4][4];
#pragma unroll
    for (int i = 0; i < 4; ++i)
#pragma unroll
        for (int j = 0; j < 4; ++j) acc[i][j] = (floatx4)0.f;
    const int fr = lane & 15, fk = (lane >> 4) * 8;

    for (int k0 = 0; k0 < 256; k0 += 32) {
        __syncthreads();
        if (k0 < 128) {
            GLL16(xbf + xrow0 + k0, As + wofs);
            GLL16(xbf + xrow1 + k0, As + wofs + 512);
        } else {
            GLL16(Ht + hrow0 + (k0 - 128), As + wofs);
            GLL16(Ht + hrow1 + (k0 - 128), As + wofs + 512);
        }
        GLL16(Af + brow0 + k0, Bs + wofs);
        GLL16(Af + brow1 + k0, Bs + wofs + 512);
        __syncthreads();
        short8 af[4], bf[4];
#pragma unroll
        for (int i = 0; i < 4; ++i) {
            af[i] = *(const short8*)&As[(mq + i * 16 + fr) * 32 + fk];
            bf[i] = *(const short8*)&Bs[(lq + i * 16 + fr) * 32 + fk];
        }
#pragma unroll
        for (int i = 0; i < 4; ++i)
#pragma unroll
            for (int j = 0; j < 4; ++j)
                acc[i][j] = __builtin_amdgcn_mfma_f32_16x16x32_bf16(
                    af[i], bf[j], acc[i][j], 0, 0, 0);
    }
#pragma unroll
    for (int i = 0; i < 4; ++i)
#pragma unroll
        for (int j = 0; j < 4; ++j)
#pragma unroll
            for (int r = 0; r < 4; ++r) {
                int c  = c0 + mq + i * 16 + (lane >> 4) * 4 + r;
                int tc = lq + j * 16 + (lane & 15);
                wyb[((size_t)(c >> 6) * 512 + n) * 8192 + (size_t)(c & 63) * 128 + tc] =
                    f2bf(acc[i][j][r]);
            }
}

// ---------------------------------------------------------------------------
extern "C" void kernel_launch(void* const* d_in, const int* in_sizes, int n_in,
                              void* d_out, int out_size, void* d_ws, size_t ws_size,
                              hipStream_t stream) {
    const float* input = (const float*)d_in[0];  // [B, C, L]
    const float* dAr   = (const float*)d_in[1];
    const float* dAi   = (const float*)d_in[2];
    const float* Bm    = (const float*)d_in[3];  // [N, C]
    const float* Cm    = (const float*)d_in[4];  // [C, N]
    const float* E     = (const float*)d_in[5];
    float* out = (float*)d_out;

    char* ws = (char*)d_ws;
    const size_t MB = 1048576;
    u16* xt   = (u16*)(ws + 0);          // 32 MB  (later overlaid by wyb)
    u16* xbf  = (u16*)(ws + 32 * MB);    // 32 MB  (later overlaid by yt)
    u16* Af   = (u16*)(ws + 64 * MB);    // 32 MB
    u16* WW   = (u16*)(ws + 96 * MB);    // 16 MB
    u16* SEf  = (u16*)(ws + 112 * MB);   // 32 MB
    u16* Ht   = (u16*)(ws + 144 * MB);   // 32 MB
    u16* Bmb  = (u16*)(ws + 176 * MB);   // 0.5 MB
    u16* Cmb  = (u16*)(ws + 177 * MB);   // 0.5 MB
    u16* wyb  = xt;                      // overlay (xt dead after gemm1)
    u16* yt   = xbf;                     // overlay (xbf dead after y_gemm)

    prep_nw<<<512, 256, 0, stream>>>(dAr, dAi, E, Af, WW, Bm, Cm, Bmb, Cmb);
    transpose_in<<<dim3(128, 8, BSZ), 256, 0, stream>>>(input, xt);
    gemm_bf16_o16<<<dim3(64, 4, BSZ), 256, 0, stream>>>(Bmb, xt, xbf);
    se_gemm<<<dim3(2, 512), 256, 0, stream>>>(xbf, WW, SEf);
    bscan<<<512, 256, 0, stream>>>(dAr, dAi, SEf, Ht);
    y_gemm<<<dim3(2, 512), 256, 0, stream>>>(xbf, Ht, Af, wyb);
    transpose_u16<<<dim3(128, 8, BSZ), 256, 0, stream>>>(wyb, yt);
    gemm_bf16_o32<<<dim3(64, 4, BSZ), 256, 0, stream>>>(Cmb, yt, out);
}

// Round 8
// 243.800 us; speedup vs baseline: 1.1167x; 1.0996x over previous
//
#include <hip/hip_runtime.h>
#include <hip/hip_bf16.h>

typedef unsigned short u16;
typedef __attribute__((ext_vector_type(8))) short short8;
typedef __attribute__((ext_vector_type(8))) unsigned short ushort8v;
typedef __attribute__((ext_vector_type(4))) float floatx4;

#define BSZ   4
#define CDIM  512
#define NDIM  512
#define SDIM  64
#define LEN   8192

__device__ __forceinline__ u16 f2bf(float x) {
    unsigned int u = __float_as_uint(x);
    unsigned int r = (u + 0x7FFFu + ((u >> 16) & 1u)) >> 16;
    return (u16)r;
}

#define GLL16(g, l)                                                          \
    __builtin_amdgcn_global_load_lds(                                        \
        (const __attribute__((address_space(1))) unsigned int*)(g),          \
        (__attribute__((address_space(3))) unsigned int*)(l), 16, 0, 0)

// ---------------------------------------------------------------------------
// Merged prep (blocks 0..511, one per n) + input transpose (blocks 512..4607).
// Independent work co-scheduled: transcendental-heavy prep overlaps
// memory-heavy transpose. Shared LDS arena (35 KB).
// ---------------------------------------------------------------------------
__global__ __launch_bounds__(256) void prep_all(const float* __restrict__ dAr,
                                                const float* __restrict__ dAi,
                                                const float* __restrict__ E,
                                                u16* __restrict__ Af,
                                                u16* __restrict__ WW,
                                                const float* __restrict__ Bmf,
                                                const float* __restrict__ Cmf,
                                                u16* __restrict__ bh,
                                                u16* __restrict__ ch,
                                                const float* __restrict__ input,
                                                u16* __restrict__ xt) {
    __shared__ __align__(16) char smem[34816];
    const int bid = blockIdx.x;
    const int t = threadIdx.x;
    if (bid < 512) {
        // ---------------- prep_nw body (verbatim), n = bid ----------------
        float* sA = (float*)smem;            // 64
        float* sW = sA + 64;                 // 64
        float* sE = sW + 64;                 // 64
        float* sK = sE + 64;                 // 128
        float (*Ms)[65] = (float (*)[65])(sK + 128);   // 128 x 65
        const int n = bid;
        if (t < 64) {
            sA[t] = dAr[n * 64 + t];
            sW[t] = dAi[n * 64 + t];
            sE[t] = E[n * 64 + t];
        }
        {
            int i = n * 512 + t * 2;
            float2 vb = *(const float2*)&Bmf[i];
            float2 vc = *(const float2*)&Cmf[i];
            ushort2 hb, hc;
            hb.x = f2bf(vb.x); hb.y = f2bf(vb.y);
            hc.x = f2bf(vc.x); hc.y = f2bf(vc.y);
            *(ushort2*)&bh[i] = hb;
            *(ushort2*)&ch[i] = hc;
        }
        __syncthreads();
        u16* Afn = Af + (size_t)n * 32768;
#pragma unroll 4
        for (int it = 0; it < 32; ++it) {
            int idx = it * 256 + t;
            int tt = idx >> 6, s = idx & 63;
            float a = sA[s], w = sW[s], e = sE[s];
            float tp1 = (float)(tt + 1);
            float sn, cs;
            __sincosf(w * tp1, &sn, &cs);
            float ea = __expf(a * tp1) * e;
            float mr = ea * cs;
            Ms[tt][s] = mr;
            Afn[tt * 256 + 128 + s] = f2bf(mr);
            Afn[tt * 256 + 192 + s] = f2bf(-ea * sn);
        }
        __syncthreads();
        if (t < 128) {
            float acc = 0.f;
            if (t == 0) {
#pragma unroll
                for (int s = 0; s < 64; ++s) acc += sE[s];
            } else {
#pragma unroll
                for (int s = 0; s < 64; ++s) acc += Ms[t - 1][s];
            }
            sK[t] = acc;
        }
        __syncthreads();
#pragma unroll 8
        for (int it = 0; it < 64; ++it) {
            int idx = it * 256 + t;
            int tt = idx >> 7, k = idx & 127;
            float v = (k <= tt) ? sK[tt - k] : 0.f;
            Afn[tt * 256 + k] = f2bf(v);
        }
        u16* WWn = WW + (size_t)n * 16384;
#pragma unroll 4
        for (int it = 0; it < 32; ++it) {
            int idx = it * 256 + t;
            int s = idx >> 7, tau = idx & 127;
            float a = sA[s], w = sW[s];
            float d = (float)(127 - tau);
            float sn, cs;
            __sincosf(w * d, &sn, &cs);
            float ea = __expf(a * d);
            WWn[s * 128 + tau] = f2bf(ea * cs);
            WWn[(s + 64) * 128 + tau] = f2bf(ea * sn);
        }
    } else {
        // ---------------- transpose_in body (verbatim), decoded -----------
        float (*tile)[65] = (float (*)[65])smem;
        const int tid = bid - 512;           // 0..4095
        const int b  = tid >> 10;            // 0..3
        const int r0 = ((tid >> 7) & 7) * 64;
        const int c0 = (tid & 127) * 64;
        const float* s = input + (size_t)b * 512 * 8192;
#pragma unroll
        for (int p = 0; p < 4; ++p) {
            int r = (t >> 4) + p * 16;
            float4 v = *(const float4*)&s[(size_t)(r0 + r) * 8192 + c0 + (t & 15) * 4];
            tile[r][(t & 15) * 4 + 0] = v.x;
            tile[r][(t & 15) * 4 + 1] = v.y;
            tile[r][(t & 15) * 4 + 2] = v.z;
            tile[r][(t & 15) * 4 + 3] = v.w;
        }
        __syncthreads();
#pragma unroll
        for (int p = 0; p < 4; ++p) {
            int i  = (t >> 4) + p * 16;
            int cb = (t & 15) * 4;
            ushort4 h;
            u16* hp = (u16*)&h;
#pragma unroll
            for (int q = 0; q < 4; ++q) hp[q] = f2bf(tile[cb + q][i]);
            *(ushort4*)&xt[((size_t)b * 8192 + c0 + i) * 512 + r0 + cb] = h;
        }
    }
}

// ---------------------------------------------------------------------------
// Transpose u16: src [B][512][8192] -> dst [B][8192][512].
// ---------------------------------------------------------------------------
__global__ __launch_bounds__(256) void transpose_u16(const u16* __restrict__ src,
                                                     u16* __restrict__ dst) {
    __shared__ u16 tile[64][72];   // 144 B rows (16B-aligned)
    const int b  = blockIdx.z;
    const int n0 = blockIdx.y * 64;
    const int l0 = blockIdx.x * 64;
    const int t  = threadIdx.x;
    const u16* s = src + (size_t)b * 512 * 8192;
    u16* d = dst + (size_t)b * 8192 * 512;
#pragma unroll
    for (int p = 0; p < 2; ++p) {
        int r = (t >> 3) + p * 32;
        *(ushort8v*)&tile[r][(t & 7) * 8] =
            *(const ushort8v*)&s[(size_t)(n0 + r) * 8192 + l0 + (t & 7) * 8];
    }
    __syncthreads();
#pragma unroll
    for (int p = 0; p < 2; ++p) {
        int li = (t >> 3) + p * 32;
        int cb = (t & 7) * 8;
        ushort8v v;
#pragma unroll
        for (int q = 0; q < 8; ++q) v[q] = tile[cb + q][li];
        *(ushort8v*)&d[(size_t)(l0 + li) * 512 + n0 + cb] = v;
    }
}

// ---------------------------------------------------------------------------
// Pure-bf16 MFMA GEMM, bf16 output. BK=64, T2 XOR-swizzled LDS. (r7-proven)
// ---------------------------------------------------------------------------
__global__ __launch_bounds__(256) void gemm_bf16_o16(const u16* __restrict__ A,
                                                     const u16* __restrict__ Xt,
                                                     u16* __restrict__ Y) {
    __shared__ u16 As[128 * 64];
    __shared__ u16 Xs[128 * 64];
    const int b    = blockIdx.z;
    const int m0   = blockIdx.y * 128;
    const int l0   = blockIdx.x * 128;
    const int t    = threadIdx.x;
    const int w    = t >> 6;
    const int lane = t & 63;
    const int mq   = (w >> 1) * 64;
    const int lq   = (w & 1) * 64;
    const u16* Xb = Xt + (size_t)b * 8192 * 512;
    const int scol = (((lane & 7) ^ (lane >> 3)) << 3);
    const size_t a_off = (size_t)(m0 + 32 * w + (lane >> 3)) * 512 + scol;
    const size_t x_off = (size_t)(l0 + 32 * w + (lane >> 3)) * 512 + scol;
    u16* AsW = As + w * 2048;
    u16* XsW = Xs + w * 2048;

    floatx4 acc[4][4];
#pragma unroll
    for (int i = 0; i < 4; ++i)
#pragma unroll
        for (int j = 0; j < 4; ++j) acc[i][j] = (floatx4)0.f;
    const int fr = lane & 15;
    const int fk = (lane >> 4) * 8;
    const int swz = (fr & 7) << 3;

    for (int k0 = 0; k0 < 512; k0 += 64) {
        __syncthreads();
#pragma unroll
        for (int g = 0; g < 4; ++g) {
            GLL16(A + a_off + g * 4096 + k0, AsW + g * 512);
            GLL16(Xb + x_off + g * 4096 + k0, XsW + g * 512);
        }
        __syncthreads();
#pragma unroll
        for (int kk = 0; kk < 64; kk += 32) {
            short8 af[4], bf[4];
            const int pc = (kk + fk) ^ swz;
#pragma unroll
            for (int i = 0; i < 4; ++i) {
                af[i] = *(const short8*)&As[(mq + i * 16 + fr) * 64 + pc];
                bf[i] = *(const short8*)&Xs[(lq + i * 16 + fr) * 64 + pc];
            }
#pragma unroll
            for (int i = 0; i < 4; ++i)
#pragma unroll
                for (int j = 0; j < 4; ++j)
                    acc[i][j] = __builtin_amdgcn_mfma_f32_16x16x32_bf16(
                        af[i], bf[j], acc[i][j], 0, 0, 0);
        }
    }
    u16* Yb = Y + (size_t)b * 512 * 8192;
#pragma unroll
    for (int i = 0; i < 4; ++i)
#pragma unroll
        for (int j = 0; j < 4; ++j)
#pragma unroll
            for (int r = 0; r < 4; ++r) {
                int mg = m0 + mq + i * 16 + (lane >> 4) * 4 + r;
                int lg = l0 + lq + j * 16 + (lane & 15);
                Yb[(size_t)mg * 8192 + lg] = f2bf(acc[i][j][r]);
            }
}

// ---------------------------------------------------------------------------
// Pure-bf16 MFMA GEMM, fp32 output. BK=64 + T2 swizzle. (r7-proven)
// ---------------------------------------------------------------------------
__global__ __launch_bounds__(256) void gemm_bf16_o32(const u16* __restrict__ A,
                                                     const u16* __restrict__ Xt,
                                                     float* __restrict__ Y) {
    __shared__ u16 As[128 * 64];
    __shared__ u16 Xs[128 * 64];
    const int b    = blockIdx.z;
    const int m0   = blockIdx.y * 128;
    const int l0   = blockIdx.x * 128;
    const int t    = threadIdx.x;
    const int w    = t >> 6;
    const int lane = t & 63;
    const int mq   = (w >> 1) * 64;
    const int lq   = (w & 1) * 64;
    const u16* Xb = Xt + (size_t)b * 8192 * 512;
    const int scol = (((lane & 7) ^ (lane >> 3)) << 3);
    const size_t a_off = (size_t)(m0 + 32 * w + (lane >> 3)) * 512 + scol;
    const size_t x_off = (size_t)(l0 + 32 * w + (lane >> 3)) * 512 + scol;
    u16* AsW = As + w * 2048;
    u16* XsW = Xs + w * 2048;

    floatx4 acc[4][4];
#pragma unroll
    for (int i = 0; i < 4; ++i)
#pragma unroll
        for (int j = 0; j < 4; ++j) acc[i][j] = (floatx4)0.f;
    const int fr = lane & 15;
    const int fk = (lane >> 4) * 8;
    const int swz = (fr & 7) << 3;

    for (int k0 = 0; k0 < 512; k0 += 64) {
        __syncthreads();
#pragma unroll
        for (int g = 0; g < 4; ++g) {
            GLL16(A + a_off + g * 4096 + k0, AsW + g * 512);
            GLL16(Xb + x_off + g * 4096 + k0, XsW + g * 512);
        }
        __syncthreads();
#pragma unroll
        for (int kk = 0; kk < 64; kk += 32) {
            short8 af[4], bf[4];
            const int pc = (kk + fk) ^ swz;
#pragma unroll
            for (int i = 0; i < 4; ++i) {
                af[i] = *(const short8*)&As[(mq + i * 16 + fr) * 64 + pc];
                bf[i] = *(const short8*)&Xs[(lq + i * 16 + fr) * 64 + pc];
            }
#pragma unroll
            for (int i = 0; i < 4; ++i)
#pragma unroll
                for (int j = 0; j < 4; ++j)
                    acc[i][j] = __builtin_amdgcn_mfma_f32_16x16x32_bf16(
                        af[i], bf[j], acc[i][j], 0, 0, 0);
        }
    }
    float* Yb = Y + (size_t)b * 512 * 8192;
#pragma unroll
    for (int i = 0; i < 4; ++i)
#pragma unroll
        for (int j = 0; j < 4; ++j)
#pragma unroll
            for (int r = 0; r < 4; ++r) {
                int mg = m0 + mq + i * 16 + (lane >> 4) * 4 + r;
                int lg = l0 + lq + j * 16 + (lane & 15);
                Yb[(size_t)mg * 8192 + lg] = acc[i][j][r];
            }
}

// ---------------------------------------------------------------------------
// SE-GEMM, c-tile 256 (one block per n): SE[c][q] = sum_tau x[c][tau]*WW[n][q][tau]
// Per wave: 128 m-rows x 64 q-cols (acc[8][4]); WW read once per n.
// ---------------------------------------------------------------------------
__global__ __launch_bounds__(256) void se_gemm(const u16* __restrict__ xbf,
                                               const u16* __restrict__ WW,
                                               u16* __restrict__ SEf) {
    __shared__ u16 As[256 * 32];   // 16 KB
    __shared__ u16 Bs[128 * 32];   // 8 KB
    const int n  = blockIdx.x;
    const int t  = threadIdx.x;
    const int w  = t >> 6, lane = t & 63;
    const int mq = (w >> 1) * 128;
    const int lq = (w & 1) * 64;
    const int ar0 = 64 * w + (lane >> 2);      // A-staging rows: 4 chunks of 16
    const int kq8 = (lane & 3) * 8;
    size_t xrow[4];
#pragma unroll
    for (int g = 0; g < 4; ++g) {
        int c = ar0 + 16 * g;
        xrow[g] = ((size_t)(c >> 6) * 512 + n) * 8192 + (size_t)(c & 63) * 128 + kq8;
    }
    const size_t brow0 = (size_t)n * 16384 + (size_t)(32 * w + (lane >> 2)) * 128 + kq8;
    const size_t brow1 = brow0 + 16 * 128;
    const int wofsA = w * 2048;
    const int wofsB = w * 1024;
    const int fr = lane & 15, fk = (lane >> 4) * 8;

    floatx4 acc[8][4];
#pragma unroll
    for (int i = 0; i < 8; ++i)
#pragma unroll
        for (int j = 0; j < 4; ++j) acc[i][j] = (floatx4)0.f;

    for (int k0 = 0; k0 < 128; k0 += 32) {
        __syncthreads();
#pragma unroll
        for (int g = 0; g < 4; ++g)
            GLL16(xbf + xrow[g] + k0, As + wofsA + g * 512);
        GLL16(WW + brow0 + k0, Bs + wofsB);
        GLL16(WW + brow1 + k0, Bs + wofsB + 512);
        __syncthreads();
        short8 bfr[4];
#pragma unroll
        for (int j = 0; j < 4; ++j)
            bfr[j] = *(const short8*)&Bs[(lq + j * 16 + fr) * 32 + fk];
#pragma unroll
        for (int i = 0; i < 8; ++i) {
            short8 af = *(const short8*)&As[(mq + i * 16 + fr) * 32 + fk];
#pragma unroll
            for (int j = 0; j < 4; ++j)
                acc[i][j] = __builtin_amdgcn_mfma_f32_16x16x32_bf16(
                    af, bfr[j], acc[i][j], 0, 0, 0);
        }
    }
#pragma unroll
    for (int i = 0; i < 8; ++i)
#pragma unroll
        for (int j = 0; j < 4; ++j)
#pragma unroll
            for (int r = 0; r < 4; ++r) {
                int c = mq + i * 16 + (lane >> 4) * 4 + r;
                int q = lq + j * 16 + fr;
                SEf[(((size_t)(c >> 6) * 512 + n) * 64 + (c & 63)) * 128 + q] =
                    f2bf(acc[i][j][r]);
            }
}

// ---------------------------------------------------------------------------
// Boundary scan: H[j+1] = z^T * H[j] + SE[j], H[0]=0; store H[j] (bf16).
// ---------------------------------------------------------------------------
__global__ __launch_bounds__(256) void bscan(const float* __restrict__ dAr,
                                             const float* __restrict__ dAi,
                                             const u16* __restrict__ SEf,
                                             u16* __restrict__ Ht) {
    const int id = blockIdx.x * 256 + threadIdx.x;
    const int s = id & 63, n = (id >> 6) & 511, b = id >> 15;
    const float a = dAr[n * 64 + s], wv = dAi[n * 64 + s];
    const float eaT = expf(a * 128.f);
    float sT, cT;
    sincosf(wv * 128.f, &sT, &cT);
    const float zTr = eaT * cT, zTi = eaT * sT;
    const size_t base = ((size_t)b * 512 + n) * 64 * 128;
    float Hr = 0.f, Hi = 0.f;
    for (int j = 0; j < 64; ++j) {
        Ht[base + j * 128 + s]      = f2bf(Hr);
        Ht[base + j * 128 + 64 + s] = f2bf(Hi);
        float ser = __uint_as_float((unsigned int)SEf[base + j * 128 + s] << 16);
        float sei = __uint_as_float((unsigned int)SEf[base + j * 128 + 64 + s] << 16);
        float nHr = fmaf(zTr, Hr, fmaf(-zTi, Hi, ser));
        float nHi = fmaf(zTi, Hr, fmaf(zTr, Hi, sei));
        Hr = nHr; Hi = nHi;
    }
}

// ---------------------------------------------------------------------------
// y-GEMM, c-tile 256 (one block per n): y[c][t] = [x ; H](c,k) dot Af[n][t][k].
// Af read once per n. As buffer reused for x (k<128) and H (k>=128).
// ---------------------------------------------------------------------------
__global__ __launch_bounds__(256) void y_gemm(const u16* __restrict__ xbf,
                                              const u16* __restrict__ Ht,
                                              const u16* __restrict__ Af,
                                              u16* __restrict__ wyb) {
    __shared__ u16 As[256 * 32];   // 16 KB
    __shared__ u16 Bs[128 * 32];   // 8 KB
    const int n  = blockIdx.x;
    const int t  = threadIdx.x;
    const int w  = t >> 6, lane = t & 63;
    const int mq = (w >> 1) * 128;
    const int lq = (w & 1) * 64;
    const int ar0 = 64 * w + (lane >> 2);
    const int kq8 = (lane & 3) * 8;
    size_t xrow[4], hrow[4];
#pragma unroll
    for (int g = 0; g < 4; ++g) {
        int c = ar0 + 16 * g;
        xrow[g] = ((size_t)(c >> 6) * 512 + n) * 8192 + (size_t)(c & 63) * 128 + kq8;
        hrow[g] = (((size_t)(c >> 6) * 512 + n) * 64 + (c & 63)) * 128 + kq8;
    }
    const size_t brow0 = (size_t)n * 32768 + (size_t)(32 * w + (lane >> 2)) * 256 + kq8;
    const size_t brow1 = brow0 + 16 * 256;
    const int wofsA = w * 2048;
    const int wofsB = w * 1024;
    const int fr = lane & 15, fk = (lane >> 4) * 8;

    floatx4 acc[8][4];
#pragma unroll
    for (int i = 0; i < 8; ++i)
#pragma unroll
        for (int j = 0; j < 4; ++j) acc[i][j] = (floatx4)0.f;

    for (int k0 = 0; k0 < 256; k0 += 32) {
        __syncthreads();
        if (k0 < 128) {
#pragma unroll
            for (int g = 0; g < 4; ++g)
                GLL16(xbf + xrow[g] + k0, As + wofsA + g * 512);
        } else {
#pragma unroll
            for (int g = 0; g < 4; ++g)
                GLL16(Ht + hrow[g] + (k0 - 128), As + wofsA + g * 512);
        }
        GLL16(Af + brow0 + k0, Bs + wofsB);
        GLL16(Af + brow1 + k0, Bs + wofsB + 512);
        __syncthreads();
        short8 bfr[4];
#pragma unroll
        for (int j = 0; j < 4; ++j)
            bfr[j] = *(const short8*)&Bs[(lq + j * 16 + fr) * 32 + fk];
#pragma unroll
        for (int i = 0; i < 8; ++i) {
            short8 af = *(const short8*)&As[(mq + i * 16 + fr) * 32 + fk];
#pragma unroll
            for (int j = 0; j < 4; ++j)
                acc[i][j] = __builtin_amdgcn_mfma_f32_16x16x32_bf16(
                    af, bfr[j], acc[i][j], 0, 0, 0);
        }
    }
#pragma unroll
    for (int i = 0; i < 8; ++i)
#pragma unroll
        for (int j = 0; j < 4; ++j)
#pragma unroll
            for (int r = 0; r < 4; ++r) {
                int c  = mq + i * 16 + (lane >> 4) * 4 + r;
                int tc = lq + j * 16 + fr;
                wyb[((size_t)(c >> 6) * 512 + n) * 8192 + (size_t)(c & 63) * 128 + tc] =
                    f2bf(acc[i][j][r]);
            }
}

// ---------------------------------------------------------------------------
extern "C" void kernel_launch(void* const* d_in, const int* in_sizes, int n_in,
                              void* d_out, int out_size, void* d_ws, size_t ws_size,
                              hipStream_t stream) {
    const float* input = (const float*)d_in[0];  // [B, C, L]
    const float* dAr   = (const float*)d_in[1];
    const float* dAi   = (const float*)d_in[2];
    const float* Bm    = (const float*)d_in[3];  // [N, C]
    const float* Cm    = (const float*)d_in[4];  // [C, N]
    const float* E     = (const float*)d_in[5];
    float* out = (float*)d_out;

    char* ws = (char*)d_ws;
    const size_t MB = 1048576;
    u16* xt   = (u16*)(ws + 0);          // 32 MB  (later overlaid by wyb)
    u16* xbf  = (u16*)(ws + 32 * MB);    // 32 MB  (later overlaid by yt)
    u16* Af   = (u16*)(ws + 64 * MB);    // 32 MB
    u16* WW   = (u16*)(ws + 96 * MB);    // 16 MB
    u16* SEf  = (u16*)(ws + 112 * MB);   // 32 MB
    u16* Ht   = (u16*)(ws + 144 * MB);   // 32 MB
    u16* Bmb  = (u16*)(ws + 176 * MB);   // 0.5 MB
    u16* Cmb  = (u16*)(ws + 177 * MB);   // 0.5 MB
    u16* wyb  = xt;                      // overlay (xt dead after gemm1)
    u16* yt   = xbf;                     // overlay (xbf dead after y_gemm)

    prep_all<<<4608, 256, 0, stream>>>(dAr, dAi, E, Af, WW, Bm, Cm, Bmb, Cmb,
                                       input, xt);
    gemm_bf16_o16<<<dim3(64, 4, BSZ), 256, 0, stream>>>(Bmb, xt, xbf);
    se_gemm<<<512, 256, 0, stream>>>(xbf, WW, SEf);
    bscan<<<512, 256, 0, stream>>>(dAr, dAi, SEf, Ht);
    y_gemm<<<512, 256, 0, stream>>>(xbf, Ht, Af, wyb);
    transpose_u16<<<dim3(128, 8, BSZ), 256, 0, stream>>>(wyb, yt);
    gemm_bf16_o32<<<dim3(64, 4, BSZ), 256, 0, stream>>>(Cmb, yt, out);
}